// Round 2
// baseline (498.129 us; speedup 1.0000x reference)
//
#include <hip/hip_runtime.h>
#include <hip/hip_bf16.h>
#include <cstdint>
#include <cmath>

// Gemma3 attention, MI355X/gfx950.  Round 8: gemm256 rebuilt as a 4-slot
// LDS ring (BK=32) with COUNTED vmcnt(8) tile-boundary waits (T4) -- staging
// runs 3 tiles ahead so the wait retires loads issued ~4 phases earlier,
// covering HBM latency.  R1's drain-vmcnt(0) depth-1 pipeline measured
// MfmaUtil 33%; counted-wait is the isolated +38-73% lever (m218).
// B=2, L=2048, H=2560, Hq=8, Hkv=4, D=256, window = last 512 keys.
// Workspace 75.5 MB:
//   [0,21.0M)   xb (4096x2560 bf16)     -> sc (4x2048x512 fp32) after projs
//   [21.0,41.9) qkvwb (4096x2560 bf16: q|k|v rows) ; rows 0-2047 -> owb after QKV
//   [41.9,58.7) q_ws (4096x2048) [attn aliases]   [58.7,67.1) k_ws
//   [67.1,75.5) vT ((b,kvh,d) x 2048)

using bf16 = __hip_bfloat16;
typedef __attribute__((ext_vector_type(8))) short short8;
typedef __attribute__((ext_vector_type(4))) float f32x4;

__device__ inline void gl_lds16(const void* g, void* l) {
  __builtin_amdgcn_global_load_lds(
      (const __attribute__((address_space(1))) unsigned int*)g,
      (__attribute__((address_space(3))) unsigned int*)l, 16, 0, 0);
}

// fp32 -> bf16 (RNE), 4 elems/thread
__global__ __launch_bounds__(256)
void cvt_bf16(const float4* __restrict__ in, __hip_bfloat162* __restrict__ out,
              int n4) {
  const int i = blockIdx.x * 256 + threadIdx.x;
  if (i < n4) {
    const float4 v = in[i];
    __hip_bfloat162 lo, hi;
    lo.x = __float2bfloat16(v.x); lo.y = __float2bfloat16(v.y);
    hi.x = __float2bfloat16(v.z); hi.y = __float2bfloat16(v.w);
    out[2 * i] = lo;
    out[2 * i + 1] = hi;
  }
}

// ---------------------------------------------------------------------------
// 256x256 GEMM, 4-slot ring, BK=32.  C[m][n] = sum_k A[m][k]*B[n][k], bf16.
// 512 threads = 8 waves (2M x 4N), per-wave 128x64 output.  LDS 128 KiB =
// 4 ring slots x (A 256x32 + B 256x32) bf16.  2 phases/tile (16 MFMA each):
//   phase A: ds_read a0-3,b0-3 | stage A of tile t+3 -> bar -> MFMA -> bar
//   phase B: ds_read a4-7      | stage B of tile t+3 -> MFMA -> vmcnt(8) -> bar
// Staging 3 tiles ahead; vmcnt(8) retires exactly tile t+1 (in-order VMEM
// counter), issued during tile t-2 => ~4 phases of latency cover.  Slot
// (t+3)&3 was consumed at tile t-1 => write-after-read safe across the
// end-of-(t-1) barrier.  Swizzle: 16B-slot ^= (row&3) applied to BOTH the
// per-lane global source col (LDS dest stays linear for global_load_lds)
// and the ds_read address (same involution; R1 measured 0 conflicts).
// EPI 0: QKV router -> C0=q_ws (ld 2048), C1=k_ws (ld 1024), C2=vT transposed.
// EPI 1: fp32 C row-major, ld = ldc.
// ---------------------------------------------------------------------------
template <int EPI>
__global__ __launch_bounds__(512, 2)
void gemm256(const bf16* __restrict__ A, const bf16* __restrict__ B,
             void* __restrict__ C0, void* __restrict__ C1,
             void* __restrict__ C2, int K, int lda, int ldb, int ldc) {
  extern __shared__ short lds[];
  short* As = lds;            // 4 slots x 8192 shorts (256 rows x 32 cols)
  short* Bs = lds + 32768;
  const int t = threadIdx.x;
  const int lane = t & 63;
  const int wid = t >> 6, wm = wid >> 2, wn = wid & 3;
  const int m16 = lane & 15, quad = lane >> 4;
  const int brow = blockIdx.y * 256, bcol = blockIdx.x * 256;

  // Staging: round r (0/1) covers tile rows r*128 + (t>>2), linear 16B slot
  // (t&3); source col pre-swizzled by row&3 so swizzled reads see the right
  // data (involution both sides).
  const int srow = t >> 2;                        // 0..127
  const int scol = ((t & 3) ^ (srow & 3)) * 8;    // elems
  const bf16* gA0 = A + (size_t)(brow + srow) * lda + scol;
  const bf16* gA1 = A + (size_t)(brow + 128 + srow) * lda + scol;
  const bf16* gB0 = B + (size_t)(bcol + srow) * ldb + scol;
  const bf16* gB1 = B + (size_t)(bcol + 128 + srow) * ldb + scol;
  const int dst = t * 8;  // shorts

  // ds_read addressing: row r, swizzled slot = quad ^ (r&3); r&3 == m16&3.
  const int rbA = (wm * 128 + m16) * 32;
  const int rbB = (wn * 64 + m16) * 32;
  const int sw = (quad ^ (m16 & 3)) * 8;

  f32x4 acc[8][4] = {};
  short8 a[8], b[4];

  const int nkt = K >> 5;
  // ---- prologue: stage tiles 0,1,2 (12 loads); retire tile 0 ----
#pragma unroll
  for (int p = 0; p < 3; ++p) {
    const int o = p * 32;
    short* sa = As + p * 8192;
    short* sb = Bs + p * 8192;
    gl_lds16(gA0 + o, sa + dst);
    gl_lds16(gA1 + o, sa + 4096 + dst);
    gl_lds16(gB0 + o, sb + dst);
    gl_lds16(gB1 + o, sb + 4096 + dst);
  }
  asm volatile("s_waitcnt vmcnt(8)" ::: "memory");
  asm volatile("s_barrier" ::: "memory");

  for (int kt = 0; kt < nkt; ++kt) {
    const short* Ab = As + (kt & 3) * 8192;
    const short* Bb = Bs + (kt & 3) * 8192;
    const bool pre = (kt + 3) < nkt;
    const int po = (kt + 3) << 5;
    short* pa = As + ((kt + 3) & 3) * 8192;
    short* pb = Bs + ((kt + 3) & 3) * 8192;

    // ---- phase A: quadrants (mi 0-3) x (nj 0-3) ----
#pragma unroll
    for (int mi = 0; mi < 4; ++mi)
      a[mi] = *(const short8*)&Ab[rbA + mi * 512 + sw];
#pragma unroll
    for (int nj = 0; nj < 4; ++nj)
      b[nj] = *(const short8*)&Bb[rbB + nj * 512 + sw];
    if (pre) {
      gl_lds16(gA0 + po, pa + dst);
      gl_lds16(gA1 + po, pa + 4096 + dst);
    }
    asm volatile("s_barrier" ::: "memory");
    __builtin_amdgcn_s_setprio(1);
#pragma unroll
    for (int mi = 0; mi < 4; ++mi)
#pragma unroll
      for (int nj = 0; nj < 4; ++nj)
        acc[mi][nj] = __builtin_amdgcn_mfma_f32_16x16x32_bf16(
            a[mi], b[nj], acc[mi][nj], 0, 0, 0);
    __builtin_amdgcn_s_setprio(0);
    asm volatile("s_barrier" ::: "memory");

    // ---- phase B: quadrants (mi 4-7) x (nj 0-3); tile-boundary wait ----
#pragma unroll
    for (int mi = 4; mi < 8; ++mi)
      a[mi] = *(const short8*)&Ab[rbA + mi * 512 + sw];
    if (pre) {
      gl_lds16(gB0 + po, pb + dst);
      gl_lds16(gB1 + po, pb + 4096 + dst);
    }
    asm volatile("s_barrier" ::: "memory");
    __builtin_amdgcn_s_setprio(1);
#pragma unroll
    for (int mi = 4; mi < 8; ++mi)
#pragma unroll
      for (int nj = 0; nj < 4; ++nj)
        acc[mi][nj] = __builtin_amdgcn_mfma_f32_16x16x32_bf16(
            a[mi], b[nj], acc[mi][nj], 0, 0, 0);
    __builtin_amdgcn_s_setprio(0);
    // Retire tile kt+1 (oldest 4 outstanding loads).  Outstanding here:
    // steady (staged kt+3): tiles kt+1,kt+2,kt+3 = 12 -> vmcnt(8);
    // kt+3==nkt: 8 -> vmcnt(4);  kt+2==nkt: 4 -> vmcnt(0);  last tile: none.
    if (kt + 4 <= nkt) {
      asm volatile("s_waitcnt vmcnt(8)" ::: "memory");
    } else if (kt + 3 == nkt) {
      asm volatile("s_waitcnt vmcnt(4)" ::: "memory");
    } else if (kt + 2 == nkt) {
      asm volatile("s_waitcnt vmcnt(0)" ::: "memory");
    }
    asm volatile("s_barrier" ::: "memory");
  }

  // ---- epilogue ----
  const int row0 = brow + wm * 128 + quad * 4;
  const int col0 = bcol + wn * 64 + m16;
#pragma unroll
  for (int mi = 0; mi < 8; ++mi) {
#pragma unroll
    for (int ni = 0; ni < 4; ++ni) {
      const int col = col0 + ni * 16;
#pragma unroll
      for (int r = 0; r < 4; ++r) {
        const int row = row0 + mi * 16 + r;
        const float v = acc[mi][ni][r];
        if constexpr (EPI == 0) {
          // col tiles are 256-wide; 2048/3072 boundaries are block-uniform
          if (col < 2048) {
            ((bf16*)C0)[(size_t)row * 2048 + col] = __float2bfloat16(v);
          } else if (col < 3072) {
            ((bf16*)C1)[(size_t)row * 1024 + (col - 2048)] = __float2bfloat16(v);
          } else {
            const int b2 = row >> 11;
            ((bf16*)C2)[((size_t)(b2 * 1024 + (col - 3072))) * 2048 +
                        (row & 2047)] = __float2bfloat16(v);
          }
        } else {
          ((float*)C0)[(size_t)row * ldc + col] = v;
        }
      }
    }
  }
}

// ---------------------------------------------------------------------------
// 128x128 GEMM (proven m97 structure) - kept for attention-inner matmuls.
// C[m][n] = sum_k A[m][k]*B[n][k], bf16 operands, K-contiguous both sides.
// Grid (N/128, M/128, zh). A += zh*sAh; B += (zh>>1)*sBh; C elem off zh*sCh.
// EPI 0: bf16 C row-major.  EPI 1: fp32 C, scale+softcap (scores).
// ---------------------------------------------------------------------------
template <int EPI>
__global__ __launch_bounds__(256)
void gemm(const bf16* __restrict__ A, const bf16* __restrict__ B,
          void* __restrict__ Cv, int K, int lda, int ldb, int ldc,
          long sAh, long sBh, long sCh, float cscale) {
  __shared__ short As[4096];  // 128 x 32 bf16
  __shared__ short Bs[4096];
  const int t = threadIdx.x, lane = t & 63, w = t >> 6;
  const int zh = blockIdx.z;
  A += (size_t)zh * sAh;
  B += (size_t)(zh >> 1) * sBh;
  const size_t coff = (size_t)zh * sCh;
  const int blockRow = blockIdx.y * 128, blockCol = blockIdx.x * 128;

  const int e = t * 8;
  const int srow = t >> 2, scol = (t & 3) * 8;
  const bf16* gA0 = A + (size_t)(blockRow + srow) * lda + scol;
  const bf16* gA1 = gA0 + (size_t)64 * lda;
  const bf16* gB0 = B + (size_t)(blockCol + srow) * ldb + scol;
  const bf16* gB1 = gB0 + (size_t)64 * ldb;

  const int wm = w >> 1, wn = w & 1;
  const int quad = lane >> 4, m16 = lane & 15;
  f32x4 acc[4][4] = {};

  for (int kt = 0; kt < K; kt += 32) {
    __syncthreads();
    gl_lds16(gA0 + kt, &As[e]);
    gl_lds16(gA1 + kt, &As[e + 2048]);
    gl_lds16(gB0 + kt, &Bs[e]);
    gl_lds16(gB1 + kt, &Bs[e + 2048]);
    __syncthreads();
    short8 af[4], bfr[4];
#pragma unroll
    for (int i = 0; i < 4; ++i)
      af[i] = *(const short8*)&As[(wm * 64 + i * 16 + m16) * 32 + quad * 8];
#pragma unroll
    for (int j = 0; j < 4; ++j)
      bfr[j] = *(const short8*)&Bs[(wn * 64 + j * 16 + m16) * 32 + quad * 8];
#pragma unroll
    for (int i = 0; i < 4; ++i)
#pragma unroll
      for (int j = 0; j < 4; ++j)
        acc[i][j] = __builtin_amdgcn_mfma_f32_16x16x32_bf16(af[i], bfr[j],
                                                            acc[i][j], 0, 0, 0);
  }

#pragma unroll
  for (int i = 0; i < 4; ++i) {
#pragma unroll
    for (int j = 0; j < 4; ++j) {
      const int gcol = blockCol + wn * 64 + j * 16 + m16;
#pragma unroll
      for (int r = 0; r < 4; ++r) {
        const int grow = blockRow + wm * 64 + i * 16 + quad * 4 + r;
        float v = acc[i][j][r] * cscale;
        if constexpr (EPI == 1) {
          // softcap 50*tanh(v/50) via expf; mask zeros, window structural
          const float y = v * 0.02f;
          const float ee = __expf(-2.0f * fabsf(y));
          v = copysignf(50.0f * (1.0f - ee) / (1.0f + ee), y);
          ((float*)Cv)[coff + (size_t)grow * ldc + gcol] = v;
        } else {
          ((bf16*)Cv)[coff + (size_t)grow * ldc + gcol] = __float2bfloat16(v);
        }
      }
    }
  }
}

// One wave per 256-elem head vector, in place. hmod: heads per token row.
__global__ __launch_bounds__(256)
void norm_rope(bf16* __restrict__ qk, const float* __restrict__ nw, int hmod) {
  const int seg = blockIdx.x * 4 + (threadIdx.x >> 6);
  const int lane = threadIdx.x & 63;
  bf16* p = qk + (size_t)seg * 256;
  float x0 = __bfloat162float(p[lane]);
  float x1 = __bfloat162float(p[lane + 64]);
  float x2 = __bfloat162float(p[lane + 128]);
  float x3 = __bfloat162float(p[lane + 192]);
  float ss = x0 * x0 + x1 * x1 + x2 * x2 + x3 * x3;
#pragma unroll
  for (int o = 32; o; o >>= 1) ss += __shfl_xor(ss, o);
  const float r = rsqrtf(ss * (1.0f / 256.0f) + 1e-6f);
  const float n0 = x0 * r * (1.0f + nw[lane]);
  const float n1 = x1 * r * (1.0f + nw[lane + 64]);
  const float n2 = x2 * r * (1.0f + nw[lane + 128]);
  const float n3 = x3 * r * (1.0f + nw[lane + 192]);
  const int l = (seg / hmod) & 2047;
  const float kf = -9.210340371976184f / 128.0f;  // -ln(10000)/128
  float c0, s0, c1, s1;
  sincosf((float)l * expf(kf * (float)lane), &s0, &c0);
  sincosf((float)l * expf(kf * (float)(lane + 64)), &s1, &c1);
  p[lane]       = __float2bfloat16(n0 * c0 - n2 * s0);
  p[lane + 128] = __float2bfloat16(n2 * c0 + n0 * s0);
  p[lane + 64]  = __float2bfloat16(n1 * c1 - n3 * s1);
  p[lane + 192] = __float2bfloat16(n3 * c1 + n1 * s1);
}

// One wave per 512-wide fp32 score row; bf16 P written IN PLACE (row stride
// 1024 bf16 elems).
__global__ __launch_bounds__(256)
void softmax_k(float* __restrict__ S) {
  const int row = blockIdx.x * 4 + (threadIdx.x >> 6);
  const int lane = threadIdx.x & 63;
  float* rowp = S + (size_t)row * 512;
  const float4 a = ((const float4*)rowp)[lane];
  const float4 b = ((const float4*)rowp)[lane + 64];
  float mx = fmaxf(fmaxf(fmaxf(a.x, a.y), fmaxf(a.z, a.w)),
                   fmaxf(fmaxf(b.x, b.y), fmaxf(b.z, b.w)));
#pragma unroll
  for (int o = 32; o; o >>= 1) mx = fmaxf(mx, __shfl_xor(mx, o));
  float e0 = expf(a.x - mx), e1 = expf(a.y - mx);
  float e2 = expf(a.z - mx), e3 = expf(a.w - mx);
  float f0 = expf(b.x - mx), f1 = expf(b.y - mx);
  float f2 = expf(b.z - mx), f3 = expf(b.w - mx);
  float sum = e0 + e1 + e2 + e3 + f0 + f1 + f2 + f3;
#pragma unroll
  for (int o = 32; o; o >>= 1) sum += __shfl_xor(sum, o);
  const float inv = 1.0f / sum;
  bf16* p0 = (bf16*)rowp + lane * 4;
  p0[0] = __float2bfloat16(e0 * inv);
  p0[1] = __float2bfloat16(e1 * inv);
  p0[2] = __float2bfloat16(e2 * inv);
  p0[3] = __float2bfloat16(e3 * inv);
  bf16* p1 = p0 + 256;
  p1[0] = __float2bfloat16(f0 * inv);
  p1[1] = __float2bfloat16(f1 * inv);
  p1[2] = __float2bfloat16(f2 * inv);
  p1[3] = __float2bfloat16(f3 * inv);
}

extern "C" void kernel_launch(void* const* d_in, const int* in_sizes, int n_in,
                              void* d_out, int out_size, void* d_ws, size_t ws_size,
                              hipStream_t stream) {
  const float* x    = (const float*)d_in[0];
  const float* q_w  = (const float*)d_in[2];
  const float* k_w  = (const float*)d_in[3];
  const float* v_w  = (const float*)d_in[4];
  const float* o_w  = (const float*)d_in[5];
  const float* q_nw = (const float*)d_in[6];
  const float* k_nw = (const float*)d_in[7];
  float* out = (float*)d_out;

  char* wsb = (char*)d_ws;
  bf16* xb    = (bf16*)(wsb);             // 4096x2560
  float* sc   = (float*)(wsb);            // aliases xb after projections
  bf16* qkvwb = (bf16*)(wsb + 20971520);  // 4096x2560 (q 0-2047|k|v rows)
  bf16* owb   = qkvwb;                    // aliases q-rows after QKV proj
  bf16* kwb   = (bf16*)(wsb + 31457280);  // rows 2048-3071
  bf16* vwb   = (bf16*)(wsb + 36700160);  // rows 3072-4095
  bf16* q_ws  = (bf16*)(wsb + 41943040);  // 4096x2048
  bf16* k_ws  = (bf16*)(wsb + 58720256);  // 4096x1024
  bf16* vT    = (bf16*)(wsb + 67108864);  // (b,kvh,d)x2048
  bf16* attn  = q_ws;  // PV(b,c) writes exactly the cols scores(b,c) consumed

  static bool attr_set = false;
  if (!attr_set) {
    (void)hipFuncSetAttribute(reinterpret_cast<const void*>(&gemm256<0>),
                              hipFuncAttributeMaxDynamicSharedMemorySize, 131072);
    (void)hipFuncSetAttribute(reinterpret_cast<const void*>(&gemm256<1>),
                              hipFuncAttributeMaxDynamicSharedMemorySize, 131072);
    attr_set = true;
  }

  dim3 blk(256);
  // fp32 -> bf16 operand copies (q|k|v weight rows land contiguously)
  cvt_bf16<<<dim3(10240), blk, 0, stream>>>((const float4*)x,   (__hip_bfloat162*)xb,    2621440);
  cvt_bf16<<<dim3(5120),  blk, 0, stream>>>((const float4*)q_w, (__hip_bfloat162*)qkvwb, 1310720);
  cvt_bf16<<<dim3(2560),  blk, 0, stream>>>((const float4*)k_w, (__hip_bfloat162*)kwb,   655360);
  cvt_bf16<<<dim3(2560),  blk, 0, stream>>>((const float4*)v_w, (__hip_bfloat162*)vwb,   655360);
  // fused QKV projection: M=4096, N=4096 (q|k|v), K=2560 -> 16x16=256 blocks
  gemm256<0><<<dim3(16, 16), dim3(512), 131072, stream>>>(
      xb, qkvwb, (void*)q_ws, (void*)k_ws, (void*)vT, 2560, 2560, 2560, 0);
  // o_w -> bf16 into q-weight region (QKV done; stream-ordered)
  cvt_bf16<<<dim3(5120), blk, 0, stream>>>((const float4*)o_w, (__hip_bfloat162*)owb, 1310720);
  // RMSNorm + RoPE in place
  norm_rope<<<dim3(8192), blk, 0, stream>>>(q_ws, q_nw, 8);
  norm_rope<<<dim3(4096), blk, 0, stream>>>(k_ws, k_nw, 4);
  // attention per (batch b, 4-head chunk c); sc aliases xb (projections done)
  for (int b = 0; b < 2; ++b) {
    for (int c = 0; c < 2; ++c) {
      // scores: M=2048, N=512 keys (1536..2047), K=256
      gemm<1><<<dim3(4, 16, 4), blk, 0, stream>>>(
          q_ws + (size_t)b * 4194304 + c * 1024,
          k_ws + (size_t)b * 2097152 + 1572864 + c * 512,
          (void*)sc, 256, 2048, 1024, 512,
          256L, 256L, 1048576L, 1.0f / 16.0f);
      softmax_k<<<dim3(2048), blk, 0, stream>>>(sc);
      // attn = P@V: M=2048, N=256, K=512; P row stride 1024; vT ld 2048
      gemm<0><<<dim3(2, 16, 4), blk, 0, stream>>>(
          (const bf16*)sc,
          vT + (size_t)b * 2097152 + (size_t)c * 1048576 + 1536,
          (void*)(attn + (size_t)b * 4194304 + c * 1024), 512, 1024, 2048, 2048,
          2097152L, 524288L, 256L, 1.0f);
    }
  }
  // out = attn @ o_w^T : M=4096, N=2560, K=2048, fp32 store (10x16=160 blocks)
  gemm256<1><<<dim3(10, 16), dim3(512), 131072, stream>>>(
      attn, owb, (void*)out, nullptr, nullptr, 2048, 2048, 2048, 2560);
}

// Round 3
// 493.274 us; speedup vs baseline: 1.0098x; 1.0098x over previous
//
#include <hip/hip_runtime.h>
#include <hip/hip_bf16.h>
#include <cstdint>
#include <cmath>

// Gemma3 attention, MI355X/gfx950.  Round 9: R2's 4-slot ring + counted
// vmcnt(8) kept, with the BK=32 swizzle DEGENERACY fixed: slot = quad ^
// ((row>>1)&3) (R2's quad^(row&3) left consecutive-8-lane groups on only 4
// of 8 16B bank positions -> measured 7.86M conflicts -> regression).
// New swizzle gives all 8 positions per consecutive-8 lanes (R1-equivalent,
// 0 conflicts) while keeping the deep pipeline.
// B=2, L=2048, H=2560, Hq=8, Hkv=4, D=256, window = last 512 keys.
// Workspace 75.5 MB:
//   [0,21.0M)   xb (4096x2560 bf16)     -> sc (4x2048x512 fp32) after projs
//   [21.0,41.9) qkvwb (4096x2560 bf16: q|k|v rows) ; rows 0-2047 -> owb after QKV
//   [41.9,58.7) q_ws (4096x2048) [attn aliases]   [58.7,67.1) k_ws
//   [67.1,75.5) vT ((b,kvh,d) x 2048)

using bf16 = __hip_bfloat16;
typedef __attribute__((ext_vector_type(8))) short short8;
typedef __attribute__((ext_vector_type(4))) float f32x4;

__device__ inline void gl_lds16(const void* g, void* l) {
  __builtin_amdgcn_global_load_lds(
      (const __attribute__((address_space(1))) unsigned int*)g,
      (__attribute__((address_space(3))) unsigned int*)l, 16, 0, 0);
}

// fp32 -> bf16 (RNE), 4 elems/thread
__global__ __launch_bounds__(256)
void cvt_bf16(const float4* __restrict__ in, __hip_bfloat162* __restrict__ out,
              int n4) {
  const int i = blockIdx.x * 256 + threadIdx.x;
  if (i < n4) {
    const float4 v = in[i];
    __hip_bfloat162 lo, hi;
    lo.x = __float2bfloat16(v.x); lo.y = __float2bfloat16(v.y);
    hi.x = __float2bfloat16(v.z); hi.y = __float2bfloat16(v.w);
    out[2 * i] = lo;
    out[2 * i + 1] = hi;
  }
}

// ---------------------------------------------------------------------------
// 256x256 GEMM, 4-slot ring, BK=32.  C[m][n] = sum_k A[m][k]*B[n][k], bf16.
// 512 threads = 8 waves (2M x 4N), per-wave 128x64 output.  LDS 128 KiB =
// 4 ring slots x (A 256x32 + B 256x32) bf16.  2 phases/tile (16 MFMA each):
//   phase A: ds_read a0-3,b0-3 | stage A of tile t+3 -> bar -> MFMA -> bar
//   phase B: ds_read a4-7      | stage B of tile t+3 -> MFMA -> vmcnt(8) -> bar
// Staging 3 tiles ahead; vmcnt(8) retires exactly tile t+1 (in-order VMEM
// counter), issued during tile t-2 => ~4-6 phases of latency cover.  Slot
// (t+3)&3 was consumed at tile t-1 => write-after-read safe across the
// end-of-(t-1) barrier.
// Swizzle (R3 fix): 16B-slot ^= ((row>>1)&3), NOT (row&3).  Rows are 64 B =
// half a 128 B bank window; position = (slot, row&1).  With ^(row>>1)&3,
// each consecutive-8-lane read group covers all 8 positions (conflict-free);
// with R2's ^(row&3), parity was slaved to the XOR value -> 4 positions ->
// 7.86M measured conflicts.  Inverse swizzle pre-applied to the per-lane
// global source col (LDS dest stays linear for global_load_lds), same
// involution on the ds_read address.
// EPI 0: QKV router -> C0=q_ws (ld 2048), C1=k_ws (ld 1024), C2=vT transposed.
// EPI 1: fp32 C row-major, ld = ldc.
// ---------------------------------------------------------------------------
template <int EPI>
__global__ __launch_bounds__(512, 2)
void gemm256(const bf16* __restrict__ A, const bf16* __restrict__ B,
             void* __restrict__ C0, void* __restrict__ C1,
             void* __restrict__ C2, int K, int lda, int ldb, int ldc) {
  extern __shared__ short lds[];
  short* As = lds;            // 4 slots x 8192 shorts (256 rows x 32 cols)
  short* Bs = lds + 32768;
  const int t = threadIdx.x;
  const int lane = t & 63;
  const int wid = t >> 6, wm = wid >> 2, wn = wid & 3;
  const int m16 = lane & 15, quad = lane >> 4;
  const int brow = blockIdx.y * 256, bcol = blockIdx.x * 256;

  // Staging: thread t covers tile row (t>>2) (+128 for second load), linear
  // 16B slot (t&3); source col pre-swizzled by (row>>1)&3 (involution).
  const int srow = t >> 2;                            // 0..127
  const int scol = ((t & 3) ^ ((srow >> 1) & 3)) * 8; // elems
  const bf16* gA0 = A + (size_t)(brow + srow) * lda + scol;
  const bf16* gA1 = A + (size_t)(brow + 128 + srow) * lda + scol;
  const bf16* gB0 = B + (size_t)(bcol + srow) * ldb + scol;
  const bf16* gB1 = B + (size_t)(bcol + 128 + srow) * ldb + scol;
  const int dst = t * 8;  // shorts

  // ds_read addressing: row r, swizzled slot = quad ^ ((r>>1)&3);
  // r = base + m16 with 16-aligned base => (r>>1)&3 == (m16>>1)&3.
  const int rbA = (wm * 128 + m16) * 32;
  const int rbB = (wn * 64 + m16) * 32;
  const int sw = (quad ^ ((m16 >> 1) & 3)) * 8;

  f32x4 acc[8][4] = {};
  short8 a[8], b[4];

  const int nkt = K >> 5;
  // ---- prologue: stage tiles 0,1,2 (12 loads); retire tile 0 ----
#pragma unroll
  for (int p = 0; p < 3; ++p) {
    const int o = p * 32;
    short* sa = As + p * 8192;
    short* sb = Bs + p * 8192;
    gl_lds16(gA0 + o, sa + dst);
    gl_lds16(gA1 + o, sa + 4096 + dst);
    gl_lds16(gB0 + o, sb + dst);
    gl_lds16(gB1 + o, sb + 4096 + dst);
  }
  asm volatile("s_waitcnt vmcnt(8)" ::: "memory");
  asm volatile("s_barrier" ::: "memory");

  for (int kt = 0; kt < nkt; ++kt) {
    const short* Ab = As + (kt & 3) * 8192;
    const short* Bb = Bs + (kt & 3) * 8192;
    const bool pre = (kt + 3) < nkt;
    const int po = (kt + 3) << 5;
    short* pa = As + ((kt + 3) & 3) * 8192;
    short* pb = Bs + ((kt + 3) & 3) * 8192;

    // ---- phase A: quadrants (mi 0-3) x (nj 0-3) ----
#pragma unroll
    for (int mi = 0; mi < 4; ++mi)
      a[mi] = *(const short8*)&Ab[rbA + mi * 512 + sw];
#pragma unroll
    for (int nj = 0; nj < 4; ++nj)
      b[nj] = *(const short8*)&Bb[rbB + nj * 512 + sw];
    if (pre) {
      gl_lds16(gA0 + po, pa + dst);
      gl_lds16(gA1 + po, pa + 4096 + dst);
    }
    asm volatile("s_barrier" ::: "memory");
    __builtin_amdgcn_s_setprio(1);
#pragma unroll
    for (int mi = 0; mi < 4; ++mi)
#pragma unroll
      for (int nj = 0; nj < 4; ++nj)
        acc[mi][nj] = __builtin_amdgcn_mfma_f32_16x16x32_bf16(
            a[mi], b[nj], acc[mi][nj], 0, 0, 0);
    __builtin_amdgcn_s_setprio(0);
    asm volatile("s_barrier" ::: "memory");

    // ---- phase B: quadrants (mi 4-7) x (nj 0-3); tile-boundary wait ----
#pragma unroll
    for (int mi = 4; mi < 8; ++mi)
      a[mi] = *(const short8*)&Ab[rbA + mi * 512 + sw];
    if (pre) {
      gl_lds16(gB0 + po, pb + dst);
      gl_lds16(gB1 + po, pb + 4096 + dst);
    }
    asm volatile("s_barrier" ::: "memory");
    __builtin_amdgcn_s_setprio(1);
#pragma unroll
    for (int mi = 4; mi < 8; ++mi)
#pragma unroll
      for (int nj = 0; nj < 4; ++nj)
        acc[mi][nj] = __builtin_amdgcn_mfma_f32_16x16x32_bf16(
            a[mi], b[nj], acc[mi][nj], 0, 0, 0);
    __builtin_amdgcn_s_setprio(0);
    // Retire tile kt+1 (oldest 4 outstanding loads).  Outstanding here:
    // steady (staged kt+3): tiles kt+1,kt+2,kt+3 = 12 -> vmcnt(8);
    // kt+3==nkt: 8 -> vmcnt(4);  kt+2==nkt: 4 -> vmcnt(0);  last tile: none.
    if (kt + 4 <= nkt) {
      asm volatile("s_waitcnt vmcnt(8)" ::: "memory");
    } else if (kt + 3 == nkt) {
      asm volatile("s_waitcnt vmcnt(4)" ::: "memory");
    } else if (kt + 2 == nkt) {
      asm volatile("s_waitcnt vmcnt(0)" ::: "memory");
    }
    asm volatile("s_barrier" ::: "memory");
  }

  // ---- epilogue ----
  const int row0 = brow + wm * 128 + quad * 4;
  const int col0 = bcol + wn * 64 + m16;
#pragma unroll
  for (int mi = 0; mi < 8; ++mi) {
#pragma unroll
    for (int ni = 0; ni < 4; ++ni) {
      const int col = col0 + ni * 16;
#pragma unroll
      for (int r = 0; r < 4; ++r) {
        const int row = row0 + mi * 16 + r;
        const float v = acc[mi][ni][r];
        if constexpr (EPI == 0) {
          // col tiles are 256-wide; 2048/3072 boundaries are block-uniform
          if (col < 2048) {
            ((bf16*)C0)[(size_t)row * 2048 + col] = __float2bfloat16(v);
          } else if (col < 3072) {
            ((bf16*)C1)[(size_t)row * 1024 + (col - 2048)] = __float2bfloat16(v);
          } else {
            const int b2 = row >> 11;
            ((bf16*)C2)[((size_t)(b2 * 1024 + (col - 3072))) * 2048 +
                        (row & 2047)] = __float2bfloat16(v);
          }
        } else {
          ((float*)C0)[(size_t)row * ldc + col] = v;
        }
      }
    }
  }
}

// ---------------------------------------------------------------------------
// 128x128 GEMM (proven m97 structure) - kept for attention-inner matmuls.
// C[m][n] = sum_k A[m][k]*B[n][k], bf16 operands, K-contiguous both sides.
// Grid (N/128, M/128, zh). A += zh*sAh; B += (zh>>1)*sBh; C elem off zh*sCh.
// EPI 0: bf16 C row-major.  EPI 1: fp32 C, scale+softcap (scores).
// ---------------------------------------------------------------------------
template <int EPI>
__global__ __launch_bounds__(256)
void gemm(const bf16* __restrict__ A, const bf16* __restrict__ B,
          void* __restrict__ Cv, int K, int lda, int ldb, int ldc,
          long sAh, long sBh, long sCh, float cscale) {
  __shared__ short As[4096];  // 128 x 32 bf16
  __shared__ short Bs[4096];
  const int t = threadIdx.x, lane = t & 63, w = t >> 6;
  const int zh = blockIdx.z;
  A += (size_t)zh * sAh;
  B += (size_t)(zh >> 1) * sBh;
  const size_t coff = (size_t)zh * sCh;
  const int blockRow = blockIdx.y * 128, blockCol = blockIdx.x * 128;

  const int e = t * 8;
  const int srow = t >> 2, scol = (t & 3) * 8;
  const bf16* gA0 = A + (size_t)(blockRow + srow) * lda + scol;
  const bf16* gA1 = gA0 + (size_t)64 * lda;
  const bf16* gB0 = B + (size_t)(blockCol + srow) * ldb + scol;
  const bf16* gB1 = gB0 + (size_t)64 * ldb;

  const int wm = w >> 1, wn = w & 1;
  const int quad = lane >> 4, m16 = lane & 15;
  f32x4 acc[4][4] = {};

  for (int kt = 0; kt < K; kt += 32) {
    __syncthreads();
    gl_lds16(gA0 + kt, &As[e]);
    gl_lds16(gA1 + kt, &As[e + 2048]);
    gl_lds16(gB0 + kt, &Bs[e]);
    gl_lds16(gB1 + kt, &Bs[e + 2048]);
    __syncthreads();
    short8 af[4], bfr[4];
#pragma unroll
    for (int i = 0; i < 4; ++i)
      af[i] = *(const short8*)&As[(wm * 64 + i * 16 + m16) * 32 + quad * 8];
#pragma unroll
    for (int j = 0; j < 4; ++j)
      bfr[j] = *(const short8*)&Bs[(wn * 64 + j * 16 + m16) * 32 + quad * 8];
#pragma unroll
    for (int i = 0; i < 4; ++i)
#pragma unroll
      for (int j = 0; j < 4; ++j)
        acc[i][j] = __builtin_amdgcn_mfma_f32_16x16x32_bf16(af[i], bfr[j],
                                                            acc[i][j], 0, 0, 0);
  }

#pragma unroll
  for (int i = 0; i < 4; ++i) {
#pragma unroll
    for (int j = 0; j < 4; ++j) {
      const int gcol = blockCol + wn * 64 + j * 16 + m16;
#pragma unroll
      for (int r = 0; r < 4; ++r) {
        const int grow = blockRow + wm * 64 + i * 16 + quad * 4 + r;
        float v = acc[i][j][r] * cscale;
        if constexpr (EPI == 1) {
          // softcap 50*tanh(v/50) via expf; mask zeros, window structural
          const float y = v * 0.02f;
          const float ee = __expf(-2.0f * fabsf(y));
          v = copysignf(50.0f * (1.0f - ee) / (1.0f + ee), y);
          ((float*)Cv)[coff + (size_t)grow * ldc + gcol] = v;
        } else {
          ((bf16*)Cv)[coff + (size_t)grow * ldc + gcol] = __float2bfloat16(v);
        }
      }
    }
  }
}

// One wave per 256-elem head vector, in place. hmod: heads per token row.
__global__ __launch_bounds__(256)
void norm_rope(bf16* __restrict__ qk, const float* __restrict__ nw, int hmod) {
  const int seg = blockIdx.x * 4 + (threadIdx.x >> 6);
  const int lane = threadIdx.x & 63;
  bf16* p = qk + (size_t)seg * 256;
  float x0 = __bfloat162float(p[lane]);
  float x1 = __bfloat162float(p[lane + 64]);
  float x2 = __bfloat162float(p[lane + 128]);
  float x3 = __bfloat162float(p[lane + 192]);
  float ss = x0 * x0 + x1 * x1 + x2 * x2 + x3 * x3;
#pragma unroll
  for (int o = 32; o; o >>= 1) ss += __shfl_xor(ss, o);
  const float r = rsqrtf(ss * (1.0f / 256.0f) + 1e-6f);
  const float n0 = x0 * r * (1.0f + nw[lane]);
  const float n1 = x1 * r * (1.0f + nw[lane + 64]);
  const float n2 = x2 * r * (1.0f + nw[lane + 128]);
  const float n3 = x3 * r * (1.0f + nw[lane + 192]);
  const int l = (seg / hmod) & 2047;
  const float kf = -9.210340371976184f / 128.0f;  // -ln(10000)/128
  float c0, s0, c1, s1;
  sincosf((float)l * expf(kf * (float)lane), &s0, &c0);
  sincosf((float)l * expf(kf * (float)(lane + 64)), &s1, &c1);
  p[lane]       = __float2bfloat16(n0 * c0 - n2 * s0);
  p[lane + 128] = __float2bfloat16(n2 * c0 + n0 * s0);
  p[lane + 64]  = __float2bfloat16(n1 * c1 - n3 * s1);
  p[lane + 192] = __float2bfloat16(n3 * c1 + n1 * s1);
}

// One wave per 512-wide fp32 score row; bf16 P written IN PLACE (row stride
// 1024 bf16 elems).
__global__ __launch_bounds__(256)
void softmax_k(float* __restrict__ S) {
  const int row = blockIdx.x * 4 + (threadIdx.x >> 6);
  const int lane = threadIdx.x & 63;
  float* rowp = S + (size_t)row * 512;
  const float4 a = ((const float4*)rowp)[lane];
  const float4 b = ((const float4*)rowp)[lane + 64];
  float mx = fmaxf(fmaxf(fmaxf(a.x, a.y), fmaxf(a.z, a.w)),
                   fmaxf(fmaxf(b.x, b.y), fmaxf(b.z, b.w)));
#pragma unroll
  for (int o = 32; o; o >>= 1) mx = fmaxf(mx, __shfl_xor(mx, o));
  float e0 = expf(a.x - mx), e1 = expf(a.y - mx);
  float e2 = expf(a.z - mx), e3 = expf(a.w - mx);
  float f0 = expf(b.x - mx), f1 = expf(b.y - mx);
  float f2 = expf(b.z - mx), f3 = expf(b.w - mx);
  float sum = e0 + e1 + e2 + e3 + f0 + f1 + f2 + f3;
#pragma unroll
  for (int o = 32; o; o >>= 1) sum += __shfl_xor(sum, o);
  const float inv = 1.0f / sum;
  bf16* p0 = (bf16*)rowp + lane * 4;
  p0[0] = __float2bfloat16(e0 * inv);
  p0[1] = __float2bfloat16(e1 * inv);
  p0[2] = __float2bfloat16(e2 * inv);
  p0[3] = __float2bfloat16(e3 * inv);
  bf16* p1 = p0 + 256;
  p1[0] = __float2bfloat16(f0 * inv);
  p1[1] = __float2bfloat16(f1 * inv);
  p1[2] = __float2bfloat16(f2 * inv);
  p1[3] = __float2bfloat16(f3 * inv);
}

extern "C" void kernel_launch(void* const* d_in, const int* in_sizes, int n_in,
                              void* d_out, int out_size, void* d_ws, size_t ws_size,
                              hipStream_t stream) {
  const float* x    = (const float*)d_in[0];
  const float* q_w  = (const float*)d_in[2];
  const float* k_w  = (const float*)d_in[3];
  const float* v_w  = (const float*)d_in[4];
  const float* o_w  = (const float*)d_in[5];
  const float* q_nw = (const float*)d_in[6];
  const float* k_nw = (const float*)d_in[7];
  float* out = (float*)d_out;

  char* wsb = (char*)d_ws;
  bf16* xb    = (bf16*)(wsb);             // 4096x2560
  float* sc   = (float*)(wsb);            // aliases xb after projections
  bf16* qkvwb = (bf16*)(wsb + 20971520);  // 4096x2560 (q 0-2047|k|v rows)
  bf16* owb   = qkvwb;                    // aliases q-rows after QKV proj
  bf16* kwb   = (bf16*)(wsb + 31457280);  // rows 2048-3071
  bf16* vwb   = (bf16*)(wsb + 36700160);  // rows 3072-4095
  bf16* q_ws  = (bf16*)(wsb + 41943040);  // 4096x2048
  bf16* k_ws  = (bf16*)(wsb + 58720256);  // 4096x1024
  bf16* vT    = (bf16*)(wsb + 67108864);  // (b,kvh,d)x2048
  bf16* attn  = q_ws;  // PV(b,c) writes exactly the cols scores(b,c) consumed

  static bool attr_set = false;
  if (!attr_set) {
    (void)hipFuncSetAttribute(reinterpret_cast<const void*>(&gemm256<0>),
                              hipFuncAttributeMaxDynamicSharedMemorySize, 131072);
    (void)hipFuncSetAttribute(reinterpret_cast<const void*>(&gemm256<1>),
                              hipFuncAttributeMaxDynamicSharedMemorySize, 131072);
    attr_set = true;
  }

  dim3 blk(256);
  // fp32 -> bf16 operand copies (q|k|v weight rows land contiguously)
  cvt_bf16<<<dim3(10240), blk, 0, stream>>>((const float4*)x,   (__hip_bfloat162*)xb,    2621440);
  cvt_bf16<<<dim3(5120),  blk, 0, stream>>>((const float4*)q_w, (__hip_bfloat162*)qkvwb, 1310720);
  cvt_bf16<<<dim3(2560),  blk, 0, stream>>>((const float4*)k_w, (__hip_bfloat162*)kwb,   655360);
  cvt_bf16<<<dim3(2560),  blk, 0, stream>>>((const float4*)v_w, (__hip_bfloat162*)vwb,   655360);
  // fused QKV projection: M=4096, N=4096 (q|k|v), K=2560 -> 16x16=256 blocks
  gemm256<0><<<dim3(16, 16), dim3(512), 131072, stream>>>(
      xb, qkvwb, (void*)q_ws, (void*)k_ws, (void*)vT, 2560, 2560, 2560, 0);
  // o_w -> bf16 into q-weight region (QKV done; stream-ordered)
  cvt_bf16<<<dim3(5120), blk, 0, stream>>>((const float4*)o_w, (__hip_bfloat162*)owb, 1310720);
  // RMSNorm + RoPE in place
  norm_rope<<<dim3(8192), blk, 0, stream>>>(q_ws, q_nw, 8);
  norm_rope<<<dim3(4096), blk, 0, stream>>>(k_ws, k_nw, 4);
  // attention per (batch b, 4-head chunk c); sc aliases xb (projections done)
  for (int b = 0; b < 2; ++b) {
    for (int c = 0; c < 2; ++c) {
      // scores: M=2048, N=512 keys (1536..2047), K=256
      gemm<1><<<dim3(4, 16, 4), blk, 0, stream>>>(
          q_ws + (size_t)b * 4194304 + c * 1024,
          k_ws + (size_t)b * 2097152 + 1572864 + c * 512,
          (void*)sc, 256, 2048, 1024, 512,
          256L, 256L, 1048576L, 1.0f / 16.0f);
      softmax_k<<<dim3(2048), blk, 0, stream>>>(sc);
      // attn = P@V: M=2048, N=256, K=512; P row stride 1024; vT ld 2048
      gemm<0><<<dim3(2, 16, 4), blk, 0, stream>>>(
          (const bf16*)sc,
          vT + (size_t)b * 2097152 + (size_t)c * 1048576 + 1536,
          (void*)(attn + (size_t)b * 4194304 + c * 1024), 512, 1024, 2048, 2048,
          2097152L, 524288L, 256L, 1.0f);
    }
  }
  // out = attn @ o_w^T : M=4096, N=2560, K=2048, fp32 store (10x16=160 blocks)
  gemm256<1><<<dim3(10, 16), dim3(512), 131072, stream>>>(
      attn, owb, (void*)out, nullptr, nullptr, 2048, 2048, 2048, 2560);
}

// Round 4
// 480.381 us; speedup vs baseline: 1.0369x; 1.0268x over previous
//
#include <hip/hip_runtime.h>
#include <hip/hip_bf16.h>
#include <cstdint>
#include <cmath>

// Gemma3 attention, MI355X/gfx950.  Round 10: gemm256 keeps R3's 4-slot ring
// + counted vmcnt + verified swizzle, but collapses the per-phase double
// barriers to ONE barrier per K-tile.  R3 post-mortem arithmetic: lockstep
// phases serialize LDS-read time (~1130cy/tile/CU) with MFMA time
// (~1240cy/tile/CU) -> 3711cy/tile measured.  Within a tile there is NO LDS
// hazard (reads hit slot kt staged 3 tiles ago; stages hit slot kt+3 last
// read at kt-1), so the phase barriers were pure serialization.  Tile-end
// wait becomes vmcnt(counted) + lgkmcnt(0) (a wave must not cross the
// barrier with its own ds_reads in flight -- s_barrier doesn't drain lgkm).
// B=2, L=2048, H=2560, Hq=8, Hkv=4, D=256, window = last 512 keys.
// Workspace 75.5 MB:
//   [0,21.0M)   xb (4096x2560 bf16)     -> sc (4x2048x512 fp32) after projs
//   [21.0,41.9) qkvwb (4096x2560 bf16: q|k|v rows) ; rows 0-2047 -> owb after QKV
//   [41.9,58.7) q_ws (4096x2048) [attn aliases]   [58.7,67.1) k_ws
//   [67.1,75.5) vT ((b,kvh,d) x 2048)

using bf16 = __hip_bfloat16;
typedef __attribute__((ext_vector_type(8))) short short8;
typedef __attribute__((ext_vector_type(4))) float f32x4;

__device__ inline void gl_lds16(const void* g, void* l) {
  __builtin_amdgcn_global_load_lds(
      (const __attribute__((address_space(1))) unsigned int*)g,
      (__attribute__((address_space(3))) unsigned int*)l, 16, 0, 0);
}

// fp32 -> bf16 (RNE), 4 elems/thread
__global__ __launch_bounds__(256)
void cvt_bf16(const float4* __restrict__ in, __hip_bfloat162* __restrict__ out,
              int n4) {
  const int i = blockIdx.x * 256 + threadIdx.x;
  if (i < n4) {
    const float4 v = in[i];
    __hip_bfloat162 lo, hi;
    lo.x = __float2bfloat16(v.x); lo.y = __float2bfloat16(v.y);
    hi.x = __float2bfloat16(v.z); hi.y = __float2bfloat16(v.w);
    out[2 * i] = lo;
    out[2 * i + 1] = hi;
  }
}

// ---------------------------------------------------------------------------
// 256x256 GEMM, 4-slot ring, BK=32, ONE barrier per K-tile.
// C[m][n] = sum_k A[m][k]*B[n][k], bf16.  512 threads = 8 waves (2M x 4N),
// per-wave 128x64 output.  LDS 128 KiB = 4 ring slots x (A 256x32 + B 256x32).
// Per K-tile: {12 ds_read_b128 | 4 gl_lds for tile kt+3 | 32 MFMA (compiler
// fine-grained lgkmcnt overlaps MFMA with reads) | vmcnt(8)+lgkmcnt(0) | bar}.
// Ring hazards: reads hit slot kt (staged 3 tiles ago, retired by the counted
// vmcnt at tile kt-1's end); stages hit slot (kt+3)&3, last READ at tile kt-1,
// separated by the kt-1 tile barrier + per-wave lgkmcnt(0) drain.
// Swizzle (verified 0-conflict in R3): 16B-slot ^= ((row>>1)&3), inverse
// pre-applied to the per-lane global source col (LDS dest stays linear for
// global_load_lds), same involution on the ds_read address.
// EPI 0: QKV router -> C0=q_ws (ld 2048), C1=k_ws (ld 1024), C2=vT transposed.
// EPI 1: fp32 C row-major, ld = ldc.
// ---------------------------------------------------------------------------
template <int EPI>
__global__ __launch_bounds__(512, 2)
void gemm256(const bf16* __restrict__ A, const bf16* __restrict__ B,
             void* __restrict__ C0, void* __restrict__ C1,
             void* __restrict__ C2, int K, int lda, int ldb, int ldc) {
  extern __shared__ short lds[];
  short* As = lds;            // 4 slots x 8192 shorts (256 rows x 32 cols)
  short* Bs = lds + 32768;
  const int t = threadIdx.x;
  const int lane = t & 63;
  const int wid = t >> 6, wm = wid >> 2, wn = wid & 3;
  const int m16 = lane & 15, quad = lane >> 4;
  const int brow = blockIdx.y * 256, bcol = blockIdx.x * 256;

  // Staging: thread t covers tile row (t>>2) (+128 for second load), linear
  // 16B slot (t&3); source col pre-swizzled by (row>>1)&3 (involution).
  const int srow = t >> 2;                            // 0..127
  const int scol = ((t & 3) ^ ((srow >> 1) & 3)) * 8; // elems
  const bf16* gA0 = A + (size_t)(brow + srow) * lda + scol;
  const bf16* gA1 = A + (size_t)(brow + 128 + srow) * lda + scol;
  const bf16* gB0 = B + (size_t)(bcol + srow) * ldb + scol;
  const bf16* gB1 = B + (size_t)(bcol + 128 + srow) * ldb + scol;
  const int dst = t * 8;  // shorts

  // ds_read addressing: row r, swizzled slot = quad ^ ((r>>1)&3);
  // r = base + m16 with 16-aligned base => (r>>1)&3 == (m16>>1)&3.
  const int rbA = (wm * 128 + m16) * 32;
  const int rbB = (wn * 64 + m16) * 32;
  const int sw = (quad ^ ((m16 >> 1) & 3)) * 8;

  f32x4 acc[8][4] = {};
  short8 a[8], b[4];

  const int nkt = K >> 5;
  // ---- prologue: stage tiles 0,1,2 (12 loads); retire tile 0 ----
#pragma unroll
  for (int p = 0; p < 3; ++p) {
    const int o = p * 32;
    short* sa = As + p * 8192;
    short* sb = Bs + p * 8192;
    gl_lds16(gA0 + o, sa + dst);
    gl_lds16(gA1 + o, sa + 4096 + dst);
    gl_lds16(gB0 + o, sb + dst);
    gl_lds16(gB1 + o, sb + 4096 + dst);
  }
  asm volatile("s_waitcnt vmcnt(8)" ::: "memory");
  asm volatile("s_barrier" ::: "memory");

  for (int kt = 0; kt < nkt; ++kt) {
    const short* Ab = As + (kt & 3) * 8192;
    const short* Bb = Bs + (kt & 3) * 8192;
    const bool pre = (kt + 3) < nkt;
    const int po = (kt + 3) << 5;
    short* pa = As + ((kt + 3) & 3) * 8192;
    short* pb = Bs + ((kt + 3) & 3) * 8192;

    // all fragment reads for this tile (b first: first MFMAs need a0+b0..b3)
#pragma unroll
    for (int nj = 0; nj < 4; ++nj)
      b[nj] = *(const short8*)&Bb[rbB + nj * 512 + sw];
#pragma unroll
    for (int mi = 0; mi < 8; ++mi)
      a[mi] = *(const short8*)&Ab[rbA + mi * 512 + sw];
    // stage tile kt+3 (slot last read at tile kt-1; WAR safe across barrier)
    if (pre) {
      gl_lds16(gA0 + po, pa + dst);
      gl_lds16(gA1 + po, pa + 4096 + dst);
      gl_lds16(gB0 + po, pb + dst);
      gl_lds16(gB1 + po, pb + 4096 + dst);
    }
    __builtin_amdgcn_s_setprio(1);
#pragma unroll
    for (int mi = 0; mi < 8; ++mi)
#pragma unroll
      for (int nj = 0; nj < 4; ++nj)
        acc[mi][nj] = __builtin_amdgcn_mfma_f32_16x16x32_bf16(
            a[mi], b[nj], acc[mi][nj], 0, 0, 0);
    __builtin_amdgcn_s_setprio(0);
    // Tile-end: retire tile kt+1's loads (counted, in-order) AND drain this
    // wave's ds_reads (s_barrier alone doesn't wait lgkm; next tile stages
    // into slot kt&3... slot (kt+4)&3 which we just read).  Outstanding VMEM:
    // steady 12 -> vmcnt(8); tails 8 -> 4 -> 0.
    if (kt + 4 <= nkt) {
      asm volatile("s_waitcnt vmcnt(8) lgkmcnt(0)" ::: "memory");
    } else if (kt + 3 == nkt) {
      asm volatile("s_waitcnt vmcnt(4) lgkmcnt(0)" ::: "memory");
    } else if (kt + 2 == nkt) {
      asm volatile("s_waitcnt vmcnt(0) lgkmcnt(0)" ::: "memory");
    } else {
      asm volatile("s_waitcnt lgkmcnt(0)" ::: "memory");
    }
    asm volatile("s_barrier" ::: "memory");
  }

  // ---- epilogue ----
  const int row0 = brow + wm * 128 + quad * 4;
  const int col0 = bcol + wn * 64 + m16;
#pragma unroll
  for (int mi = 0; mi < 8; ++mi) {
#pragma unroll
    for (int ni = 0; ni < 4; ++ni) {
      const int col = col0 + ni * 16;
#pragma unroll
      for (int r = 0; r < 4; ++r) {
        const int row = row0 + mi * 16 + r;
        const float v = acc[mi][ni][r];
        if constexpr (EPI == 0) {
          // col tiles are 256-wide; 2048/3072 boundaries are block-uniform
          if (col < 2048) {
            ((bf16*)C0)[(size_t)row * 2048 + col] = __float2bfloat16(v);
          } else if (col < 3072) {
            ((bf16*)C1)[(size_t)row * 1024 + (col - 2048)] = __float2bfloat16(v);
          } else {
            const int b2 = row >> 11;
            ((bf16*)C2)[((size_t)(b2 * 1024 + (col - 3072))) * 2048 +
                        (row & 2047)] = __float2bfloat16(v);
          }
        } else {
          ((float*)C0)[(size_t)row * ldc + col] = v;
        }
      }
    }
  }
}

// ---------------------------------------------------------------------------
// 128x128 GEMM (proven m97 structure) - kept for attention-inner matmuls.
// C[m][n] = sum_k A[m][k]*B[n][k], bf16 operands, K-contiguous both sides.
// Grid (N/128, M/128, zh). A += zh*sAh; B += (zh>>1)*sBh; C elem off zh*sCh.
// EPI 0: bf16 C row-major.  EPI 1: fp32 C, scale+softcap (scores).
// ---------------------------------------------------------------------------
template <int EPI>
__global__ __launch_bounds__(256)
void gemm(const bf16* __restrict__ A, const bf16* __restrict__ B,
          void* __restrict__ Cv, int K, int lda, int ldb, int ldc,
          long sAh, long sBh, long sCh, float cscale) {
  __shared__ short As[4096];  // 128 x 32 bf16
  __shared__ short Bs[4096];
  const int t = threadIdx.x, lane = t & 63, w = t >> 6;
  const int zh = blockIdx.z;
  A += (size_t)zh * sAh;
  B += (size_t)(zh >> 1) * sBh;
  const size_t coff = (size_t)zh * sCh;
  const int blockRow = blockIdx.y * 128, blockCol = blockIdx.x * 128;

  const int e = t * 8;
  const int srow = t >> 2, scol = (t & 3) * 8;
  const bf16* gA0 = A + (size_t)(blockRow + srow) * lda + scol;
  const bf16* gA1 = gA0 + (size_t)64 * lda;
  const bf16* gB0 = B + (size_t)(blockCol + srow) * ldb + scol;
  const bf16* gB1 = gB0 + (size_t)64 * ldb;

  const int wm = w >> 1, wn = w & 1;
  const int quad = lane >> 4, m16 = lane & 15;
  f32x4 acc[4][4] = {};

  for (int kt = 0; kt < K; kt += 32) {
    __syncthreads();
    gl_lds16(gA0 + kt, &As[e]);
    gl_lds16(gA1 + kt, &As[e + 2048]);
    gl_lds16(gB0 + kt, &Bs[e]);
    gl_lds16(gB1 + kt, &Bs[e + 2048]);
    __syncthreads();
    short8 af[4], bfr[4];
#pragma unroll
    for (int i = 0; i < 4; ++i)
      af[i] = *(const short8*)&As[(wm * 64 + i * 16 + m16) * 32 + quad * 8];
#pragma unroll
    for (int j = 0; j < 4; ++j)
      bfr[j] = *(const short8*)&Bs[(wn * 64 + j * 16 + m16) * 32 + quad * 8];
#pragma unroll
    for (int i = 0; i < 4; ++i)
#pragma unroll
      for (int j = 0; j < 4; ++j)
        acc[i][j] = __builtin_amdgcn_mfma_f32_16x16x32_bf16(af[i], bfr[j],
                                                            acc[i][j], 0, 0, 0);
  }

#pragma unroll
  for (int i = 0; i < 4; ++i) {
#pragma unroll
    for (int j = 0; j < 4; ++j) {
      const int gcol = blockCol + wn * 64 + j * 16 + m16;
#pragma unroll
      for (int r = 0; r < 4; ++r) {
        const int grow = blockRow + wm * 64 + i * 16 + quad * 4 + r;
        float v = acc[i][j][r] * cscale;
        if constexpr (EPI == 1) {
          // softcap 50*tanh(v/50) via expf; mask zeros, window structural
          const float y = v * 0.02f;
          const float ee = __expf(-2.0f * fabsf(y));
          v = copysignf(50.0f * (1.0f - ee) / (1.0f + ee), y);
          ((float*)Cv)[coff + (size_t)grow * ldc + gcol] = v;
        } else {
          ((bf16*)Cv)[coff + (size_t)grow * ldc + gcol] = __float2bfloat16(v);
        }
      }
    }
  }
}

// One wave per 256-elem head vector, in place. hmod: heads per token row.
__global__ __launch_bounds__(256)
void norm_rope(bf16* __restrict__ qk, const float* __restrict__ nw, int hmod) {
  const int seg = blockIdx.x * 4 + (threadIdx.x >> 6);
  const int lane = threadIdx.x & 63;
  bf16* p = qk + (size_t)seg * 256;
  float x0 = __bfloat162float(p[lane]);
  float x1 = __bfloat162float(p[lane + 64]);
  float x2 = __bfloat162float(p[lane + 128]);
  float x3 = __bfloat162float(p[lane + 192]);
  float ss = x0 * x0 + x1 * x1 + x2 * x2 + x3 * x3;
#pragma unroll
  for (int o = 32; o; o >>= 1) ss += __shfl_xor(ss, o);
  const float r = rsqrtf(ss * (1.0f / 256.0f) + 1e-6f);
  const float n0 = x0 * r * (1.0f + nw[lane]);
  const float n1 = x1 * r * (1.0f + nw[lane + 64]);
  const float n2 = x2 * r * (1.0f + nw[lane + 128]);
  const float n3 = x3 * r * (1.0f + nw[lane + 192]);
  const int l = (seg / hmod) & 2047;
  const float kf = -9.210340371976184f / 128.0f;  // -ln(10000)/128
  float c0, s0, c1, s1;
  sincosf((float)l * expf(kf * (float)lane), &s0, &c0);
  sincosf((float)l * expf(kf * (float)(lane + 64)), &s1, &c1);
  p[lane]       = __float2bfloat16(n0 * c0 - n2 * s0);
  p[lane + 128] = __float2bfloat16(n2 * c0 + n0 * s0);
  p[lane + 64]  = __float2bfloat16(n1 * c1 - n3 * s1);
  p[lane + 192] = __float2bfloat16(n3 * c1 + n1 * s1);
}

// One wave per 512-wide fp32 score row; bf16 P written IN PLACE (row stride
// 1024 bf16 elems).
__global__ __launch_bounds__(256)
void softmax_k(float* __restrict__ S) {
  const int row = blockIdx.x * 4 + (threadIdx.x >> 6);
  const int lane = threadIdx.x & 63;
  float* rowp = S + (size_t)row * 512;
  const float4 a = ((const float4*)rowp)[lane];
  const float4 b = ((const float4*)rowp)[lane + 64];
  float mx = fmaxf(fmaxf(fmaxf(a.x, a.y), fmaxf(a.z, a.w)),
                   fmaxf(fmaxf(b.x, b.y), fmaxf(b.z, b.w)));
#pragma unroll
  for (int o = 32; o; o >>= 1) mx = fmaxf(mx, __shfl_xor(mx, o));
  float e0 = expf(a.x - mx), e1 = expf(a.y - mx);
  float e2 = expf(a.z - mx), e3 = expf(a.w - mx);
  float f0 = expf(b.x - mx), f1 = expf(b.y - mx);
  float f2 = expf(b.z - mx), f3 = expf(b.w - mx);
  float sum = e0 + e1 + e2 + e3 + f0 + f1 + f2 + f3;
#pragma unroll
  for (int o = 32; o; o >>= 1) sum += __shfl_xor(sum, o);
  const float inv = 1.0f / sum;
  bf16* p0 = (bf16*)rowp + lane * 4;
  p0[0] = __float2bfloat16(e0 * inv);
  p0[1] = __float2bfloat16(e1 * inv);
  p0[2] = __float2bfloat16(e2 * inv);
  p0[3] = __float2bfloat16(e3 * inv);
  bf16* p1 = p0 + 256;
  p1[0] = __float2bfloat16(f0 * inv);
  p1[1] = __float2bfloat16(f1 * inv);
  p1[2] = __float2bfloat16(f2 * inv);
  p1[3] = __float2bfloat16(f3 * inv);
}

extern "C" void kernel_launch(void* const* d_in, const int* in_sizes, int n_in,
                              void* d_out, int out_size, void* d_ws, size_t ws_size,
                              hipStream_t stream) {
  const float* x    = (const float*)d_in[0];
  const float* q_w  = (const float*)d_in[2];
  const float* k_w  = (const float*)d_in[3];
  const float* v_w  = (const float*)d_in[4];
  const float* o_w  = (const float*)d_in[5];
  const float* q_nw = (const float*)d_in[6];
  const float* k_nw = (const float*)d_in[7];
  float* out = (float*)d_out;

  char* wsb = (char*)d_ws;
  bf16* xb    = (bf16*)(wsb);             // 4096x2560
  float* sc   = (float*)(wsb);            // aliases xb after projections
  bf16* qkvwb = (bf16*)(wsb + 20971520);  // 4096x2560 (q 0-2047|k|v rows)
  bf16* owb   = qkvwb;                    // aliases q-rows after QKV proj
  bf16* kwb   = (bf16*)(wsb + 31457280);  // rows 2048-3071
  bf16* vwb   = (bf16*)(wsb + 36700160);  // rows 3072-4095
  bf16* q_ws  = (bf16*)(wsb + 41943040);  // 4096x2048
  bf16* k_ws  = (bf16*)(wsb + 58720256);  // 4096x1024
  bf16* vT    = (bf16*)(wsb + 67108864);  // (b,kvh,d)x2048
  bf16* attn  = q_ws;  // PV(b,c) writes exactly the cols scores(b,c) consumed

  static bool attr_set = false;
  if (!attr_set) {
    (void)hipFuncSetAttribute(reinterpret_cast<const void*>(&gemm256<0>),
                              hipFuncAttributeMaxDynamicSharedMemorySize, 131072);
    (void)hipFuncSetAttribute(reinterpret_cast<const void*>(&gemm256<1>),
                              hipFuncAttributeMaxDynamicSharedMemorySize, 131072);
    attr_set = true;
  }

  dim3 blk(256);
  // fp32 -> bf16 operand copies (q|k|v weight rows land contiguously)
  cvt_bf16<<<dim3(10240), blk, 0, stream>>>((const float4*)x,   (__hip_bfloat162*)xb,    2621440);
  cvt_bf16<<<dim3(5120),  blk, 0, stream>>>((const float4*)q_w, (__hip_bfloat162*)qkvwb, 1310720);
  cvt_bf16<<<dim3(2560),  blk, 0, stream>>>((const float4*)k_w, (__hip_bfloat162*)kwb,   655360);
  cvt_bf16<<<dim3(2560),  blk, 0, stream>>>((const float4*)v_w, (__hip_bfloat162*)vwb,   655360);
  // fused QKV projection: M=4096, N=4096 (q|k|v), K=2560 -> 16x16=256 blocks
  gemm256<0><<<dim3(16, 16), dim3(512), 131072, stream>>>(
      xb, qkvwb, (void*)q_ws, (void*)k_ws, (void*)vT, 2560, 2560, 2560, 0);
  // o_w -> bf16 into q-weight region (QKV done; stream-ordered)
  cvt_bf16<<<dim3(5120), blk, 0, stream>>>((const float4*)o_w, (__hip_bfloat162*)owb, 1310720);
  // RMSNorm + RoPE in place
  norm_rope<<<dim3(8192), blk, 0, stream>>>(q_ws, q_nw, 8);
  norm_rope<<<dim3(4096), blk, 0, stream>>>(k_ws, k_nw, 4);
  // attention per (batch b, 4-head chunk c); sc aliases xb (projections done)
  for (int b = 0; b < 2; ++b) {
    for (int c = 0; c < 2; ++c) {
      // scores: M=2048, N=512 keys (1536..2047), K=256
      gemm<1><<<dim3(4, 16, 4), blk, 0, stream>>>(
          q_ws + (size_t)b * 4194304 + c * 1024,
          k_ws + (size_t)b * 2097152 + 1572864 + c * 512,
          (void*)sc, 256, 2048, 1024, 512,
          256L, 256L, 1048576L, 1.0f / 16.0f);
      softmax_k<<<dim3(2048), blk, 0, stream>>>(sc);
      // attn = P@V: M=2048, N=256, K=512; P row stride 1024; vT ld 2048
      gemm<0><<<dim3(2, 16, 4), blk, 0, stream>>>(
          (const bf16*)sc,
          vT + (size_t)b * 2097152 + (size_t)c * 1048576 + 1536,
          (void*)(attn + (size_t)b * 4194304 + c * 1024), 512, 1024, 2048, 2048,
          2097152L, 524288L, 256L, 1.0f);
    }
  }
  // out = attn @ o_w^T : M=4096, N=2560, K=2048, fp32 store (10x16=160 blocks)
  gemm256<1><<<dim3(10, 16), dim3(512), 131072, stream>>>(
      attn, owb, (void*)out, nullptr, nullptr, 2048, 2048, 2048, 2560);
}

// Round 6
// 477.319 us; speedup vs baseline: 1.0436x; 1.0064x over previous
//
#include <hip/hip_runtime.h>
#include <hip/hip_bf16.h>
#include <cstdint>
#include <cmath>

// Gemma3 attention, MI355X/gfx950.  Round 12 = Round 11 resubmitted verbatim
// (R5 bench died in container acquisition, not in the kernel; audit found no
// hang/fault class: uniform barriers, ring hazards re-traced, cvt addressing
// in-bounds, ~230 VGPR < 256 cliff).  gemm256: 4-slot ring + counted vmcnt +
// REGISTER pipeline -- A-fragments of tile kt+1 ds_read during tile kt's
// MFMAs (slot kt+1 already resident), so MFMAs don't wait on this iter's LDS
// burst.  B single-buffered (VGPR budget), nj-outer MFMA order so only b[0]
// gates.  Retire shifted one tile earlier (vmcnt(4) steady state).
// B=2, L=2048, H=2560, Hq=8, Hkv=4, D=256, window = last 512 keys.
// Workspace 75.5 MB:
//   [0,21.0M)   xb (4096x2560 bf16)     -> sc (4x2048x512 fp32) after projs
//   [21.0,41.9) qkvwb (4096x2560 bf16: q|k|v rows) ; rows 0-2047 -> owb after QKV
//   [41.9,58.7) q_ws (4096x2048) [attn aliases]   [58.7,67.1) k_ws
//   [67.1,75.5) vT ((b,kvh,d) x 2048)

using bf16 = __hip_bfloat16;
typedef __attribute__((ext_vector_type(8))) short short8;
typedef __attribute__((ext_vector_type(4))) float f32x4;

__device__ inline void gl_lds16(const void* g, void* l) {
  __builtin_amdgcn_global_load_lds(
      (const __attribute__((address_space(1))) unsigned int*)g,
      (__attribute__((address_space(3))) unsigned int*)l, 16, 0, 0);
}

// fp32 -> bf16 (RNE) for x, q_w, k_w, v_w in ONE launch (segment by block).
__global__ __launch_bounds__(256)
void cvt_qkvx(const float4* __restrict__ x, const float4* __restrict__ qw,
              const float4* __restrict__ kw, const float4* __restrict__ vw,
              __hip_bfloat162* __restrict__ xb, __hip_bfloat162* __restrict__ qkvwb) {
  const int blk = blockIdx.x;
  const float4* src;
  __hip_bfloat162* dstb;
  int i;
  if (blk < 10240) {        // x: 2621440 float4
    src = x;    dstb = xb;             i = blk * 256 + threadIdx.x;
  } else if (blk < 15360) { // q_w: 1310720 float4
    src = qw;   dstb = qkvwb;          i = (blk - 10240) * 256 + threadIdx.x;
  } else if (blk < 17920) { // k_w: 655360 float4
    src = kw;   dstb = qkvwb + 2621440; i = (blk - 15360) * 256 + threadIdx.x;
  } else {                  // v_w: 655360 float4
    src = vw;   dstb = qkvwb + 3932160; i = (blk - 17920) * 256 + threadIdx.x;
  }
  const float4 v = src[i];
  __hip_bfloat162 lo, hi;
  lo.x = __float2bfloat16(v.x); lo.y = __float2bfloat16(v.y);
  hi.x = __float2bfloat16(v.z); hi.y = __float2bfloat16(v.w);
  dstb[2 * i] = lo;
  dstb[2 * i + 1] = hi;
}

// fp32 -> bf16 (RNE), 4 elems/thread (o_w: must run after QKV, aliasing)
__global__ __launch_bounds__(256)
void cvt_bf16(const float4* __restrict__ in, __hip_bfloat162* __restrict__ out,
              int n4) {
  const int i = blockIdx.x * 256 + threadIdx.x;
  if (i < n4) {
    const float4 v = in[i];
    __hip_bfloat162 lo, hi;
    lo.x = __float2bfloat16(v.x); lo.y = __float2bfloat16(v.y);
    hi.x = __float2bfloat16(v.z); hi.y = __float2bfloat16(v.w);
    out[2 * i] = lo;
    out[2 * i + 1] = hi;
  }
}

// ---------------------------------------------------------------------------
// 256x256 GEMM, 4-slot ring, BK=32, one barrier/tile, register-pipelined.
// C[m][n] = sum_k A[m][k]*B[n][k], bf16.  512 threads = 8 waves (2M x 4N),
// per-wave 128x64 output.  LDS 128 KiB = 4 ring slots x (A 256x32 + B 256x32).
// Iter j: {stage tile j+3 | read b(j) [4 ds_read] | read a(j+1) into the
// other reg set [8 ds_read] | 32 MFMA on a(j) (loaded LAST iter) x b(j),
// nj-outer so only b[0] gates | vmcnt(4)+lgkmcnt(0) | barrier}.
// Ring slot hazards (mod 4): MFMA regs (no LDS), b reads slot j, a reads
// slot j+1, staging writes slot j+3 -- all distinct; reads drained by the
// per-iter lgkmcnt(0) two barriers before any slot rewrite.
// Retire: end of iter j waits vmcnt(4) = tiles..j+2 landed (only j+3's 4
// loads outstanding); after the barrier ALL waves' slot j+1 data is visible
// for iter j+1's reads.  Prologue vmcnt(4) = tiles 0,1 landed.
// Swizzle (verified 0-conflict R3/R4): 16B-slot ^= ((row>>1)&3), inverse
// pre-applied to the per-lane global source col (linear LDS dest for
// global_load_lds), same involution on ds_read addresses.
// EPI 0: QKV router -> C0=q_ws (ld 2048), C1=k_ws (ld 1024), C2=vT transposed.
// EPI 1: fp32 C row-major, ld = ldc.  Requires nkt even (QKV 80, O-proj 64).
// ---------------------------------------------------------------------------
template <int EPI>
__global__ __launch_bounds__(512, 2)
void gemm256(const bf16* __restrict__ A, const bf16* __restrict__ B,
             void* __restrict__ C0, void* __restrict__ C1,
             void* __restrict__ C2, int K, int lda, int ldb, int ldc) {
  extern __shared__ short lds[];
  short* As = lds;            // 4 slots x 8192 shorts (256 rows x 32 cols)
  short* Bs = lds + 32768;
  const int t = threadIdx.x;
  const int lane = t & 63;
  const int wid = t >> 6, wm = wid >> 2, wn = wid & 3;
  const int m16 = lane & 15, quad = lane >> 4;
  const int brow = blockIdx.y * 256, bcol = blockIdx.x * 256;

  const int srow = t >> 2;                            // 0..127
  const int scol = ((t & 3) ^ ((srow >> 1) & 3)) * 8; // pre-swizzled src col
  const bf16* gA0 = A + (size_t)(brow + srow) * lda + scol;
  const bf16* gA1 = A + (size_t)(brow + 128 + srow) * lda + scol;
  const bf16* gB0 = B + (size_t)(bcol + srow) * ldb + scol;
  const bf16* gB1 = B + (size_t)(bcol + 128 + srow) * ldb + scol;
  const int dst = t * 8;  // shorts

  const int rbA = (wm * 128 + m16) * 32;
  const int rbB = (wn * 64 + m16) * 32;
  const int sw = (quad ^ ((m16 >> 1) & 3)) * 8;

  f32x4 acc[8][4] = {};
  short8 aA[8], aB[8];

  const int nkt = K >> 5;  // even by construction
  // ---- prologue: stage tiles 0,1,2; tiles 0,1 landed; read a(0) ----
#pragma unroll
  for (int p = 0; p < 3; ++p) {
    const int o = p * 32;
    short* sa = As + p * 8192;
    short* sb = Bs + p * 8192;
    gl_lds16(gA0 + o, sa + dst);
    gl_lds16(gA1 + o, sa + 4096 + dst);
    gl_lds16(gB0 + o, sb + dst);
    gl_lds16(gB1 + o, sb + 4096 + dst);
  }
  asm volatile("s_waitcnt vmcnt(4)" ::: "memory");
  asm volatile("s_barrier" ::: "memory");
#pragma unroll
  for (int mi = 0; mi < 8; ++mi)
    aA[mi] = *(const short8*)&As[rbA + mi * 512 + sw];

  auto ITER = [&](int j, short8 (&ac)[8], short8 (&an)[8]) {
    // stage tile j+3 into slot (j+3)&3 (last read at iter j-1; WAR-safe)
    if (j + 3 < nkt) {
      const int po = (j + 3) << 5;
      short* pa = As + ((j + 3) & 3) * 8192;
      short* pb = Bs + ((j + 3) & 3) * 8192;
      gl_lds16(gA0 + po, pa + dst);
      gl_lds16(gA1 + po, pa + 4096 + dst);
      gl_lds16(gB0 + po, pb + dst);
      gl_lds16(gB1 + po, pb + 4096 + dst);
    }
    // b(j) from slot j (oldest DS ops -> b[0] gates first MFMA only)
    const short* Bb = Bs + (j & 3) * 8192;
    short8 b[4];
#pragma unroll
    for (int nj = 0; nj < 4; ++nj)
      b[nj] = *(const short8*)&Bb[rbB + nj * 512 + sw];
    // a(j+1) into the other register set; slot j+1 landed (retired end j-1)
    if (j + 1 < nkt) {
      const short* An = As + ((j + 1) & 3) * 8192;
#pragma unroll
      for (int mi = 0; mi < 8; ++mi)
        an[mi] = *(const short8*)&An[rbA + mi * 512 + sw];
    }
    // MFMA on a(j) (registers from last iter) x b(j); nj-outer
    __builtin_amdgcn_s_setprio(1);
#pragma unroll
    for (int nj = 0; nj < 4; ++nj)
#pragma unroll
      for (int mi = 0; mi < 8; ++mi)
        acc[mi][nj] = __builtin_amdgcn_mfma_f32_16x16x32_bf16(
            ac[mi], b[nj], acc[mi][nj], 0, 0, 0);
    __builtin_amdgcn_s_setprio(0);
    // retire through tile j+2; drain own ds_reads; rendezvous
    if (j + 4 <= nkt) {
      asm volatile("s_waitcnt vmcnt(4) lgkmcnt(0)" ::: "memory");
    } else if (j + 3 == nkt) {
      asm volatile("s_waitcnt vmcnt(0) lgkmcnt(0)" ::: "memory");
    } else {
      asm volatile("s_waitcnt lgkmcnt(0)" ::: "memory");
    }
    asm volatile("s_barrier" ::: "memory");
  };

  for (int kt = 0; kt < nkt; kt += 2) {
    ITER(kt, aA, aB);
    ITER(kt + 1, aB, aA);
  }

  // ---- epilogue ----
  const int row0 = brow + wm * 128 + quad * 4;
  const int col0 = bcol + wn * 64 + m16;
#pragma unroll
  for (int mi = 0; mi < 8; ++mi) {
#pragma unroll
    for (int ni = 0; ni < 4; ++ni) {
      const int col = col0 + ni * 16;
#pragma unroll
      for (int r = 0; r < 4; ++r) {
        const int row = row0 + mi * 16 + r;
        const float v = acc[mi][ni][r];
        if constexpr (EPI == 0) {
          // col tiles are 256-wide; 2048/3072 boundaries are block-uniform
          if (col < 2048) {
            ((bf16*)C0)[(size_t)row * 2048 + col] = __float2bfloat16(v);
          } else if (col < 3072) {
            ((bf16*)C1)[(size_t)row * 1024 + (col - 2048)] = __float2bfloat16(v);
          } else {
            const int b2 = row >> 11;
            ((bf16*)C2)[((size_t)(b2 * 1024 + (col - 3072))) * 2048 +
                        (row & 2047)] = __float2bfloat16(v);
          }
        } else {
          ((float*)C0)[(size_t)row * ldc + col] = v;
        }
      }
    }
  }
}

// ---------------------------------------------------------------------------
// 128x128 GEMM (proven m97 structure) - kept for attention-inner matmuls.
// C[m][n] = sum_k A[m][k]*B[n][k], bf16 operands, K-contiguous both sides.
// Grid (N/128, M/128, zh). A += zh*sAh; B += (zh>>1)*sBh; C elem off zh*sCh.
// EPI 0: bf16 C row-major.  EPI 1: fp32 C, scale+softcap (scores).
// ---------------------------------------------------------------------------
template <int EPI>
__global__ __launch_bounds__(256)
void gemm(const bf16* __restrict__ A, const bf16* __restrict__ B,
          void* __restrict__ Cv, int K, int lda, int ldb, int ldc,
          long sAh, long sBh, long sCh, float cscale) {
  __shared__ short As[4096];  // 128 x 32 bf16
  __shared__ short Bs[4096];
  const int t = threadIdx.x, lane = t & 63, w = t >> 6;
  const int zh = blockIdx.z;
  A += (size_t)zh * sAh;
  B += (size_t)(zh >> 1) * sBh;
  const size_t coff = (size_t)zh * sCh;
  const int blockRow = blockIdx.y * 128, blockCol = blockIdx.x * 128;

  const int e = t * 8;
  const int srow = t >> 2, scol = (t & 3) * 8;
  const bf16* gA0 = A + (size_t)(blockRow + srow) * lda + scol;
  const bf16* gA1 = gA0 + (size_t)64 * lda;
  const bf16* gB0 = B + (size_t)(blockCol + srow) * ldb + scol;
  const bf16* gB1 = gB0 + (size_t)64 * ldb;

  const int wm = w >> 1, wn = w & 1;
  const int quad = lane >> 4, m16 = lane & 15;
  f32x4 acc[4][4] = {};

  for (int kt = 0; kt < K; kt += 32) {
    __syncthreads();
    gl_lds16(gA0 + kt, &As[e]);
    gl_lds16(gA1 + kt, &As[e + 2048]);
    gl_lds16(gB0 + kt, &Bs[e]);
    gl_lds16(gB1 + kt, &Bs[e + 2048]);
    __syncthreads();
    short8 af[4], bfr[4];
#pragma unroll
    for (int i = 0; i < 4; ++i)
      af[i] = *(const short8*)&As[(wm * 64 + i * 16 + m16) * 32 + quad * 8];
#pragma unroll
    for (int j = 0; j < 4; ++j)
      bfr[j] = *(const short8*)&Bs[(wn * 64 + j * 16 + m16) * 32 + quad * 8];
#pragma unroll
    for (int i = 0; i < 4; ++i)
#pragma unroll
      for (int j = 0; j < 4; ++j)
        acc[i][j] = __builtin_amdgcn_mfma_f32_16x16x32_bf16(af[i], bfr[j],
                                                            acc[i][j], 0, 0, 0);
  }

#pragma unroll
  for (int i = 0; i < 4; ++i) {
#pragma unroll
    for (int j = 0; j < 4; ++j) {
      const int gcol = blockCol + wn * 64 + j * 16 + m16;
#pragma unroll
      for (int r = 0; r < 4; ++r) {
        const int grow = blockRow + wm * 64 + i * 16 + quad * 4 + r;
        float v = acc[i][j][r] * cscale;
        if constexpr (EPI == 1) {
          // softcap 50*tanh(v/50) via expf; mask zeros, window structural
          const float y = v * 0.02f;
          const float ee = __expf(-2.0f * fabsf(y));
          v = copysignf(50.0f * (1.0f - ee) / (1.0f + ee), y);
          ((float*)Cv)[coff + (size_t)grow * ldc + gcol] = v;
        } else {
          ((bf16*)Cv)[coff + (size_t)grow * ldc + gcol] = __float2bfloat16(v);
        }
      }
    }
  }
}

// One wave per 256-elem head vector, in place. hmod: heads per token row.
__global__ __launch_bounds__(256)
void norm_rope(bf16* __restrict__ qk, const float* __restrict__ nw, int hmod) {
  const int seg = blockIdx.x * 4 + (threadIdx.x >> 6);
  const int lane = threadIdx.x & 63;
  bf16* p = qk + (size_t)seg * 256;
  float x0 = __bfloat162float(p[lane]);
  float x1 = __bfloat162float(p[lane + 64]);
  float x2 = __bfloat162float(p[lane + 128]);
  float x3 = __bfloat162float(p[lane + 192]);
  float ss = x0 * x0 + x1 * x1 + x2 * x2 + x3 * x3;
#pragma unroll
  for (int o = 32; o; o >>= 1) ss += __shfl_xor(ss, o);
  const float r = rsqrtf(ss * (1.0f / 256.0f) + 1e-6f);
  const float n0 = x0 * r * (1.0f + nw[lane]);
  const float n1 = x1 * r * (1.0f + nw[lane + 64]);
  const float n2 = x2 * r * (1.0f + nw[lane + 128]);
  const float n3 = x3 * r * (1.0f + nw[lane + 192]);
  const int l = (seg / hmod) & 2047;
  const float kf = -9.210340371976184f / 128.0f;  // -ln(10000)/128
  float c0, s0, c1, s1;
  sincosf((float)l * expf(kf * (float)lane), &s0, &c0);
  sincosf((float)l * expf(kf * (float)(lane + 64)), &s1, &c1);
  p[lane]       = __float2bfloat16(n0 * c0 - n2 * s0);
  p[lane + 128] = __float2bfloat16(n2 * c0 + n0 * s0);
  p[lane + 64]  = __float2bfloat16(n1 * c1 - n3 * s1);
  p[lane + 192] = __float2bfloat16(n3 * c1 + n1 * s1);
}

// One wave per 512-wide fp32 score row; bf16 P written IN PLACE (row stride
// 1024 bf16 elems).
__global__ __launch_bounds__(256)
void softmax_k(float* __restrict__ S) {
  const int row = blockIdx.x * 4 + (threadIdx.x >> 6);
  const int lane = threadIdx.x & 63;
  float* rowp = S + (size_t)row * 512;
  const float4 a = ((const float4*)rowp)[lane];
  const float4 b = ((const float4*)rowp)[lane + 64];
  float mx = fmaxf(fmaxf(fmaxf(a.x, a.y), fmaxf(a.z, a.w)),
                   fmaxf(fmaxf(b.x, b.y), fmaxf(b.z, b.w)));
#pragma unroll
  for (int o = 32; o; o >>= 1) mx = fmaxf(mx, __shfl_xor(mx, o));
  float e0 = expf(a.x - mx), e1 = expf(a.y - mx);
  float e2 = expf(a.z - mx), e3 = expf(a.w - mx);
  float f0 = expf(b.x - mx), f1 = expf(b.y - mx);
  float f2 = expf(b.z - mx), f3 = expf(b.w - mx);
  float sum = e0 + e1 + e2 + e3 + f0 + f1 + f2 + f3;
#pragma unroll
  for (int o = 32; o; o >>= 1) sum += __shfl_xor(sum, o);
  const float inv = 1.0f / sum;
  bf16* p0 = (bf16*)rowp + lane * 4;
  p0[0] = __float2bfloat16(e0 * inv);
  p0[1] = __float2bfloat16(e1 * inv);
  p0[2] = __float2bfloat16(e2 * inv);
  p0[3] = __float2bfloat16(e3 * inv);
  bf16* p1 = p0 + 256;
  p1[0] = __float2bfloat16(f0 * inv);
  p1[1] = __float2bfloat16(f1 * inv);
  p1[2] = __float2bfloat16(f2 * inv);
  p1[3] = __float2bfloat16(f3 * inv);
}

extern "C" void kernel_launch(void* const* d_in, const int* in_sizes, int n_in,
                              void* d_out, int out_size, void* d_ws, size_t ws_size,
                              hipStream_t stream) {
  const float* x    = (const float*)d_in[0];
  const float* q_w  = (const float*)d_in[2];
  const float* k_w  = (const float*)d_in[3];
  const float* v_w  = (const float*)d_in[4];
  const float* o_w  = (const float*)d_in[5];
  const float* q_nw = (const float*)d_in[6];
  const float* k_nw = (const float*)d_in[7];
  float* out = (float*)d_out;

  char* wsb = (char*)d_ws;
  bf16* xb    = (bf16*)(wsb);             // 4096x2560
  float* sc   = (float*)(wsb);            // aliases xb after projections
  bf16* qkvwb = (bf16*)(wsb + 20971520);  // 4096x2560 (q 0-2047|k|v rows)
  bf16* owb   = qkvwb;                    // aliases q-rows after QKV proj
  bf16* q_ws  = (bf16*)(wsb + 41943040);  // 4096x2048
  bf16* k_ws  = (bf16*)(wsb + 58720256);  // 4096x1024
  bf16* vT    = (bf16*)(wsb + 67108864);  // (b,kvh,d)x2048
  bf16* attn  = q_ws;  // PV(b,c) writes exactly the cols scores(b,c) consumed

  static bool attr_set = false;
  if (!attr_set) {
    (void)hipFuncSetAttribute(reinterpret_cast<const void*>(&gemm256<0>),
                              hipFuncAttributeMaxDynamicSharedMemorySize, 131072);
    (void)hipFuncSetAttribute(reinterpret_cast<const void*>(&gemm256<1>),
                              hipFuncAttributeMaxDynamicSharedMemorySize, 131072);
    attr_set = true;
  }

  dim3 blk(256);
  // fp32 -> bf16 operand copies: x + q|k|v weights in one launch
  cvt_qkvx<<<dim3(20480), blk, 0, stream>>>(
      (const float4*)x, (const float4*)q_w, (const float4*)k_w,
      (const float4*)v_w, (__hip_bfloat162*)xb, (__hip_bfloat162*)qkvwb);
  // fused QKV projection: M=4096, N=4096 (q|k|v), K=2560 -> 16x16=256 blocks
  gemm256<0><<<dim3(16, 16), dim3(512), 131072, stream>>>(
      xb, qkvwb, (void*)q_ws, (void*)k_ws, (void*)vT, 2560, 2560, 2560, 0);
  // o_w -> bf16 into q-weight region (QKV done; stream-ordered)
  cvt_bf16<<<dim3(5120), blk, 0, stream>>>((const float4*)o_w, (__hip_bfloat162*)owb, 1310720);
  // RMSNorm + RoPE in place
  norm_rope<<<dim3(8192), blk, 0, stream>>>(q_ws, q_nw, 8);
  norm_rope<<<dim3(4096), blk, 0, stream>>>(k_ws, k_nw, 4);
  // attention per (batch b, 4-head chunk c); sc aliases xb (projections done)
  for (int b = 0; b < 2; ++b) {
    for (int c = 0; c < 2; ++c) {
      // scores: M=2048, N=512 keys (1536..2047), K=256
      gemm<1><<<dim3(4, 16, 4), blk, 0, stream>>>(
          q_ws + (size_t)b * 4194304 + c * 1024,
          k_ws + (size_t)b * 2097152 + 1572864 + c * 512,
          (void*)sc, 256, 2048, 1024, 512,
          256L, 256L, 1048576L, 1.0f / 16.0f);
      softmax_k<<<dim3(2048), blk, 0, stream>>>(sc);
      // attn = P@V: M=2048, N=256, K=512; P row stride 1024; vT ld 2048
      gemm<0><<<dim3(2, 16, 4), blk, 0, stream>>>(
          (const bf16*)sc,
          vT + (size_t)b * 2097152 + (size_t)c * 1048576 + 1536,
          (void*)(attn + (size_t)b * 4194304 + c * 1024), 512, 1024, 2048, 2048,
          2097152L, 524288L, 256L, 1.0f);
    }
  }
  // out = attn @ o_w^T : M=4096, N=2560, K=2048, fp32 store (10x16=160 blocks)
  gemm256<1><<<dim3(10, 16), dim3(512), 131072, stream>>>(
      attn, owb, (void*)out, nullptr, nullptr, 2048, 2048, 2048, 2560);
}